// Round 2
// baseline (891.444 us; speedup 1.0000x reference)
//
#include <hip/hip_runtime.h>
#include <hip/hip_cooperative_groups.h>
#include <cstdint>

namespace cg = cooperative_groups;

// Problem constants
#define BB   8
#define CC   19
#define HWP  524288          // H*W pixels per batch row
#define NPIX 4194304         // B*H*W
#define KSEL 131072          // int(0.25 * HWP)

// Cooperative config: 1024 blocks x 256 thr, 16 px/thread (4 float4 groups).
// VGPR=92 -> 5 waves/SIMD HW occupancy -> co-residency cap 1280 blocks; 1024 is safe.
#define CNBLK 1024
#define CBPR  128            // blocks per batch row
#define CNTHR 256
#define CGRP  4

// Fallback config
#define GRID 4096

// ws layout:
//   [0, 16 MiB)  loss float[NPIX]   (fallback path only)
//   ctrl (u32 words) after:
#define LOSS_BYTES (NPIX * 4)
#define H1_OFF   0                       // hist1: 8*2048
#define H2_OFF   (8*2048)                // hist2: 8*4096
#define H3_OFF   (H2_OFF + 8*4096)      // hist3: 8*256
#define SEL1_OFF (H3_OFF + 8*256)       // 51200
#define CNT1_OFF (SEL1_OFF + 8)
#define SEL2_OFF (CNT1_OFF + 8)
#define CNT2_OFF (SEL2_OFF + 8)
#define PAD_OFF  (CNT2_OFF + 8)
#define SUMA_OFF (PAD_OFF + 2)          // word offset even -> byte offset %8==0
#define CTRL_WORDS (SUMA_OFF + 16)      // 8 doubles = 16 words

// ---------- block-level primitives (256 threads) ----------

__device__ __forceinline__ uint32_t block_incl_scan_u32(uint32_t v, volatile uint32_t* wt) {
    int lane = threadIdx.x & 63, wid = threadIdx.x >> 6;
    uint32_t inc = v;
#pragma unroll
    for (int off = 1; off < 64; off <<= 1) {
        uint32_t t = __shfl_up(inc, off);
        if (lane >= off) inc += t;
    }
    __syncthreads();                 // protect wt reuse across calls
    if (lane == 63) wt[wid] = inc;
    __syncthreads();
    for (int w = 0; w < wid; w++) inc += wt[w];
    return inc;
}

__device__ __forceinline__ double block_reduce_double(double v, volatile double* dwt) {
    int lane = threadIdx.x & 63, wid = threadIdx.x >> 6;
#pragma unroll
    for (int off = 32; off > 0; off >>= 1) v += __shfl_down(v, off);
    __syncthreads();
    if (lane == 0) dwt[wid] = v;
    __syncthreads();
    return dwt[0] + dwt[1] + dwt[2] + dwt[3];
}

__device__ __forceinline__ void block_sum_atomic(double sum, double* dst, volatile double* dwt) {
    double t = block_reduce_double(sum, dwt);
    if (threadIdx.x == 0 && t != 0.0) atomicAdd(dst, t);
}

// Descending radix-select over one row's NBINS histogram; every block computes
// its own row's answer (redundant across blocks of a row, L2-hot reads).
// Exactly one thread fires (sum over bins >= KSEL - prev >= 1 by construction).
template <int NBINS>
__device__ __forceinline__ void row_select(
    const uint32_t* __restrict__ hrow, uint32_t prev,
    volatile uint32_t* wt, volatile uint32_t* shSel, volatile uint32_t* shCnt,
    uint32_t& sel, uint32_t& cnt)
{
    constexpr int CH = NBINS / 256;
    int base = NBINS - CH * ((int)threadIdx.x + 1);   // thread 0 owns TOP bins
    uint32_t hloc[CH];
    uint32_t csum = 0;
#pragma unroll
    for (int i = 0; i < CH; i++) { hloc[i] = hrow[base + i]; csum += hloc[i]; }
    uint32_t incl = block_incl_scan_u32(csum, wt);
    uint32_t pre = incl - csum;                       // count strictly above my chunk
    uint32_t target = (uint32_t)KSEL - prev;
    if (pre < target && pre + csum >= target) {
        uint32_t cum = pre;
#pragma unroll
        for (int i = CH - 1; i >= 0; i--) {
            uint32_t h = hloc[i];
            if (cum + h >= target) { *shSel = (uint32_t)(base + i); *shCnt = prev + cum; break; }
            cum += h;
        }
    }
    __syncthreads();
    sel = *shSel; cnt = *shCnt;
}

// ---------- single cooperative kernel: everything fused, loss in registers ----

__global__ __launch_bounds__(CNTHR, 4) void topk_ce_coop(
    const float* __restrict__ logits, const int* __restrict__ labels,
    uint32_t* __restrict__ ctrl, float* __restrict__ out)
{
    cg::grid_group grid = cg::this_grid();
    __shared__ uint32_t lh[4096];      // unioned hist buffer (2048 / 4096 / 256)
    __shared__ uint32_t wt[4];
    __shared__ double dwt[4];
    __shared__ uint32_t shSel, shCnt;

    uint32_t* hist1 = ctrl + H1_OFF;
    uint32_t* hist2 = ctrl + H2_OFF;
    uint32_t* hist3 = ctrl + H3_OFF;
    uint32_t* sel1g = ctrl + SEL1_OFF;
    uint32_t* sel2g = ctrl + SEL2_OFF;
    uint32_t* cnt2g = ctrl + CNT2_OFF;
    double* sumAbove = (double*)(ctrl + SUMA_OFF);

    const int tid = threadIdx.x;
    const int b = (int)blockIdx.x / CBPR;             // batch row
    const int rowblk = (int)blockIdx.x & (CBPR - 1);

    // in-kernel zero of ctrl (poison-proof); completion guaranteed by sync #1
    for (int i = (int)blockIdx.x * CNTHR + tid; i < CTRL_WORDS; i += CNBLK * CNTHR)
        ctrl[i] = 0u;
    for (int i = tid; i < 2048; i += CNTHR) lh[i] = 0u;
    __syncthreads();

    // ---- phase 1: CE loss (exact same math as verified kernel) + top-12-bit LDS hist
    const size_t rowbase = (size_t)b * CC * HWP;
    const size_t labbase = (size_t)b * HWP;
    const int prow0 = rowblk * (CNTHR * 4 * CGRP) + tid * 4;

    float4 lr[CGRP];
#pragma unroll
    for (int g = 0; g < CGRP; g++) {
        const int prow = prow0 + g * (CNTHR * 4);
        const float4* lg = (const float4*)(logits + rowbase + prow);
        const int4 lab = *(const int4*)(labels + labbase + prow);
        float4 a[CC];
#pragma unroll
        for (int c = 0; c < CC; c++) a[c] = lg[(size_t)c * (HWP / 4)];

        float mx0 = a[0].x, mx1 = a[0].y, mx2 = a[0].z, mx3 = a[0].w;
#pragma unroll
        for (int c = 1; c < CC; c++) {
            mx0 = fmaxf(mx0, a[c].x); mx1 = fmaxf(mx1, a[c].y);
            mx2 = fmaxf(mx2, a[c].z); mx3 = fmaxf(mx3, a[c].w);
        }
        float g0 = 0.f, g1 = 0.f, g2 = 0.f, g3 = 0.f;
        float e0 = 0.f, e1 = 0.f, e2 = 0.f, e3 = 0.f;
#pragma unroll
        for (int c = 0; c < CC; c++) {
            e0 += __expf(a[c].x - mx0); e1 += __expf(a[c].y - mx1);
            e2 += __expf(a[c].z - mx2); e3 += __expf(a[c].w - mx3);
            g0 = (lab.x == c) ? a[c].x : g0;
            g1 = (lab.y == c) ? a[c].y : g1;
            g2 = (lab.z == c) ? a[c].z : g2;
            g3 = (lab.w == c) ? a[c].w : g3;
        }
        float l0 = fmaxf(mx0 + __logf(e0) - g0, 0.f);
        float l1 = fmaxf(mx1 + __logf(e1) - g1, 0.f);
        float l2 = fmaxf(mx2 + __logf(e2) - g2, 0.f);
        float l3 = fmaxf(mx3 + __logf(e3) - g3, 0.f);
        lr[g] = make_float4(l0, l1, l2, l3);

        atomicAdd(&lh[__float_as_uint(l0) >> 20], 1u);
        atomicAdd(&lh[__float_as_uint(l1) >> 20], 1u);
        atomicAdd(&lh[__float_as_uint(l2) >> 20], 1u);
        atomicAdd(&lh[__float_as_uint(l3) >> 20], 1u);
    }
    __syncthreads();
    grid.sync();                                   // #1: ctrl zeroing complete everywhere
    for (int i = tid; i < 2048; i += CNTHR) {
        uint32_t v = lh[i];
        if (v) atomicAdd(&hist1[b * 2048 + i], v);
    }
    grid.sync();                                   // #2: hist1 complete

    // ---- phase 2: local sel1, sum-above + mid-12-bit hist (loss from registers)
    uint32_t sel1v, cnt1v;
    row_select<2048>(hist1 + b * 2048, 0u, wt, &shSel, &shCnt, sel1v, cnt1v);
    __syncthreads();
    for (int i = tid; i < 4096; i += CNTHR) lh[i] = 0u;
    __syncthreads();

    double sum = 0.0;
#pragma unroll
    for (int g = 0; g < CGRP; g++) {
        float vv[4] = {lr[g].x, lr[g].y, lr[g].z, lr[g].w};
#pragma unroll
        for (int j = 0; j < 4; j++) {
            uint32_t u = __float_as_uint(vv[j]);
            uint32_t t = u >> 20;
            if (t > sel1v) sum += (double)vv[j];
            else if (t == sel1v) atomicAdd(&lh[(u >> 8) & 0xFFFu], 1u);
        }
    }
    __syncthreads();
    block_sum_atomic(sum, &sumAbove[b], dwt);
    for (int i = tid; i < 4096; i += CNTHR) {
        uint32_t v = lh[i];
        if (v) atomicAdd(&hist2[b * 4096 + i], v);
    }
    if (rowblk == 0 && tid == 0) sel1g[b] = sel1v;
    grid.sync();                                   // #3: hist2 complete

    // ---- phase 3: local sel2, sum-above + exact low-8-bit hist
    uint32_t sel2v, cnt2v;
    row_select<4096>(hist2 + b * 4096, cnt1v, wt, &shSel, &shCnt, sel2v, cnt2v);
    __syncthreads();
    lh[tid] = 0u;
    __syncthreads();

    double sum2 = 0.0;
#pragma unroll
    for (int g = 0; g < CGRP; g++) {
        float vv[4] = {lr[g].x, lr[g].y, lr[g].z, lr[g].w};
#pragma unroll
        for (int j = 0; j < 4; j++) {
            uint32_t u = __float_as_uint(vv[j]);
            if ((u >> 20) == sel1v) {
                uint32_t mid = (u >> 8) & 0xFFFu;
                if (mid > sel2v) sum2 += (double)vv[j];
                else if (mid == sel2v) atomicAdd(&lh[u & 0xFFu], 1u);
            }
        }
    }
    __syncthreads();
    block_sum_atomic(sum2, &sumAbove[b], dwt);
    {
        uint32_t c = lh[tid];
        if (c) atomicAdd(&hist3[b * 256 + tid], c);
    }
    if (rowblk == 0 && tid == 0) { sel2g[b] = sel2v; cnt2g[b] = cnt2v; }
    grid.sync();                                   // #4: hist3 + sumAbove complete

    // ---- finalize: block 0, tie-corrected closed-form top-k mean
    if (blockIdx.x == 0) {
        double tot = 0.0;
        for (int r = 0; r < BB; r++) {
            int b3 = 255 - tid;
            uint32_t h = hist3[r * 256 + b3];
            uint32_t incl = block_incl_scan_u32(h, wt);
            uint32_t pre = incl - h;
            uint32_t rem = (uint32_t)KSEL - cnt2g[r];
            uint32_t take = (rem > pre) ? ((rem - pre < h) ? (rem - pre) : h) : 0u;
            uint32_t P = (sel1g[r] << 20) | (sel2g[r] << 8) | (uint32_t)b3;
            double contrib = (double)take * (double)__uint_as_float(P);
            double s = block_reduce_double(contrib, dwt);
            if (tid == 0) tot += s + sumAbove[r];
        }
        if (tid == 0) out[0] = (float)(tot / ((double)BB * (double)KSEL));
    }
}

// ================= fallback: previous verified 6-kernel pipeline ==============

__global__ __launch_bounds__(256) void loss_hist1(
    const float* __restrict__ logits, const int* __restrict__ labels,
    float* __restrict__ loss, uint32_t* __restrict__ hist1)
{
    __shared__ uint32_t lh[2048];
    for (int i = threadIdx.x; i < 2048; i += 256) lh[i] = 0u;
    __syncthreads();

    int b = blockIdx.x >> 9;
    int pix0 = blockIdx.x * 1024 + threadIdx.x * 4;
    int prow = pix0 & (HWP - 1);

    const float4* lg = (const float4*)(logits + (size_t)b * CC * HWP + prow);
    float4 a[CC];
#pragma unroll
    for (int c = 0; c < CC; c++) a[c] = lg[(size_t)c * (HWP / 4)];

    int4 lab = *(const int4*)(labels + pix0);

    float mx0 = a[0].x, mx1 = a[0].y, mx2 = a[0].z, mx3 = a[0].w;
#pragma unroll
    for (int c = 1; c < CC; c++) {
        mx0 = fmaxf(mx0, a[c].x); mx1 = fmaxf(mx1, a[c].y);
        mx2 = fmaxf(mx2, a[c].z); mx3 = fmaxf(mx3, a[c].w);
    }
    float g0 = 0.f, g1 = 0.f, g2 = 0.f, g3 = 0.f;
    float e0 = 0.f, e1 = 0.f, e2 = 0.f, e3 = 0.f;
#pragma unroll
    for (int c = 0; c < CC; c++) {
        e0 += __expf(a[c].x - mx0); e1 += __expf(a[c].y - mx1);
        e2 += __expf(a[c].z - mx2); e3 += __expf(a[c].w - mx3);
        g0 = (lab.x == c) ? a[c].x : g0;
        g1 = (lab.y == c) ? a[c].y : g1;
        g2 = (lab.z == c) ? a[c].z : g2;
        g3 = (lab.w == c) ? a[c].w : g3;
    }
    float l0 = fmaxf(mx0 + __logf(e0) - g0, 0.f);
    float l1 = fmaxf(mx1 + __logf(e1) - g1, 0.f);
    float l2 = fmaxf(mx2 + __logf(e2) - g2, 0.f);
    float l3 = fmaxf(mx3 + __logf(e3) - g3, 0.f);

    float4 o; o.x = l0; o.y = l1; o.z = l2; o.w = l3;
    *(float4*)(loss + pix0) = o;

    atomicAdd(&lh[__float_as_uint(l0) >> 20], 1u);
    atomicAdd(&lh[__float_as_uint(l1) >> 20], 1u);
    atomicAdd(&lh[__float_as_uint(l2) >> 20], 1u);
    atomicAdd(&lh[__float_as_uint(l3) >> 20], 1u);

    __syncthreads();
    for (int i = threadIdx.x; i < 2048; i += 256) {
        uint32_t v = lh[i];
        if (v) atomicAdd(&hist1[b * 2048 + i], v);
    }
}

template <int NBINS>
__global__ __launch_bounds__(256) void scan_k(
    const uint32_t* __restrict__ hist, const uint32_t* __restrict__ cntPrev,
    uint32_t* __restrict__ selOut, uint32_t* __restrict__ cntOut)
{
    __shared__ uint32_t wt[4];
    constexpr int CH = NBINS / 256;
    int r = blockIdx.x;
    const uint32_t* hrow = hist + r * NBINS;
    int base = NBINS - CH * ((int)threadIdx.x + 1);
    uint32_t hloc[CH];
    uint32_t csum = 0;
#pragma unroll
    for (int i = 0; i < CH; i++) { hloc[i] = hrow[base + i]; csum += hloc[i]; }
    uint32_t incl = block_incl_scan_u32(csum, wt);
    uint32_t pre = incl - csum;
    uint32_t prev = cntPrev ? cntPrev[r] : 0u;
    uint32_t target = (uint32_t)KSEL - prev;
    if (pre < target && pre + csum >= target) {
        uint32_t cum = pre;
#pragma unroll
        for (int i = CH - 1; i >= 0; i--) {
            uint32_t h = hloc[i];
            if (cum + h >= target) { selOut[r] = (uint32_t)(base + i); cntOut[r] = prev + cum; break; }
            cum += h;
        }
    }
}

__global__ __launch_bounds__(256) void refine2(
    const float* __restrict__ loss, uint32_t* __restrict__ hist2,
    const uint32_t* __restrict__ sel1, double* __restrict__ sumAbove)
{
    __shared__ uint32_t lh[4096];
    __shared__ double dwt[4];
    for (int i = threadIdx.x; i < 4096; i += 256) lh[i] = 0u;
    __syncthreads();

    int b = blockIdx.x >> 9;
    uint32_t s1 = sel1[b];
    int pix0 = blockIdx.x * 1024 + threadIdx.x * 4;
    float4 v = *(const float4*)(loss + pix0);

    double sum = 0.0;
    {
        float vv[4] = {v.x, v.y, v.z, v.w};
#pragma unroll
        for (int j = 0; j < 4; j++) {
            uint32_t u = __float_as_uint(vv[j]);
            uint32_t t = u >> 20;
            if (t > s1) sum += (double)vv[j];
            else if (t == s1) atomicAdd(&lh[(u >> 8) & 0xFFFu], 1u);
        }
    }
    __syncthreads();
    block_sum_atomic(sum, &sumAbove[b], dwt);
    for (int i = threadIdx.x; i < 4096; i += 256) {
        uint32_t c = lh[i];
        if (c) atomicAdd(&hist2[b * 4096 + i], c);
    }
}

__global__ __launch_bounds__(256) void refine3(
    const float* __restrict__ loss, uint32_t* __restrict__ hist3,
    const uint32_t* __restrict__ sel1, const uint32_t* __restrict__ sel2,
    double* __restrict__ sumAbove)
{
    __shared__ uint32_t lh[256];
    __shared__ double dwt[4];
    lh[threadIdx.x] = 0u;
    __syncthreads();

    int b = blockIdx.x >> 9;
    uint32_t s1 = sel1[b], s2 = sel2[b];
    int pix0 = blockIdx.x * 1024 + threadIdx.x * 4;
    float4 v = *(const float4*)(loss + pix0);

    double sum = 0.0;
    {
        float vv[4] = {v.x, v.y, v.z, v.w};
#pragma unroll
        for (int j = 0; j < 4; j++) {
            uint32_t u = __float_as_uint(vv[j]);
            if ((u >> 20) == s1) {
                uint32_t mid = (u >> 8) & 0xFFFu;
                if (mid > s2) sum += (double)vv[j];
                else if (mid == s2) atomicAdd(&lh[u & 0xFFu], 1u);
            }
        }
    }
    __syncthreads();
    block_sum_atomic(sum, &sumAbove[b], dwt);
    {
        uint32_t c = lh[threadIdx.x];
        if (c) atomicAdd(&hist3[b * 256 + threadIdx.x], c);
    }
}

__global__ __launch_bounds__(256) void finalize_k(
    const uint32_t* __restrict__ hist3,
    const uint32_t* __restrict__ sel1, const uint32_t* __restrict__ sel2,
    const uint32_t* __restrict__ cnt2, const double* __restrict__ sumAbove,
    float* __restrict__ out)
{
    __shared__ uint32_t wt[4];
    __shared__ double dwt[4];
    double tot = 0.0;
    for (int r = 0; r < BB; r++) {
        int b3 = 255 - (int)threadIdx.x;
        uint32_t h = hist3[r * 256 + b3];
        uint32_t incl = block_incl_scan_u32(h, wt);
        uint32_t pre = incl - h;
        uint32_t rem = (uint32_t)KSEL - cnt2[r];
        uint32_t take = (rem > pre) ? ((rem - pre < h) ? (rem - pre) : h) : 0u;
        uint32_t P = (sel1[r] << 20) | (sel2[r] << 8) | (uint32_t)b3;
        double contrib = (double)take * (double)__uint_as_float(P);
        double s = block_reduce_double(contrib, dwt);
        if (threadIdx.x == 0) tot += s + sumAbove[r];
    }
    if (threadIdx.x == 0) out[0] = (float)(tot / ((double)BB * (double)KSEL));
}

extern "C" void kernel_launch(void* const* d_in, const int* in_sizes, int n_in,
                              void* d_out, int out_size, void* d_ws, size_t ws_size,
                              hipStream_t stream)
{
    const float* logits = (const float*)d_in[0];
    const int* labels   = (const int*)d_in[1];
    float* out          = (float*)d_out;

    char* ws = (char*)d_ws;
    float* loss      = (float*)ws;                   // fallback only
    uint32_t* ctrl   = (uint32_t*)(ws + LOSS_BYTES);
    uint32_t* hist1  = ctrl + H1_OFF;
    uint32_t* hist2  = ctrl + H2_OFF;
    uint32_t* hist3  = ctrl + H3_OFF;
    uint32_t* sel1   = ctrl + SEL1_OFF;
    uint32_t* cnt1   = ctrl + CNT1_OFF;
    uint32_t* sel2   = ctrl + SEL2_OFF;
    uint32_t* cnt2   = ctrl + CNT2_OFF;
    double* sumAbove = (double*)(ctrl + SUMA_OFF);

    // Primary: single cooperative kernel (zeroes ctrl in-kernel, no memset needed)
    {
        const float* a0 = logits;
        const int*   a1 = labels;
        uint32_t*    a2 = ctrl;
        float*       a3 = out;
        void* args[4] = { (void*)&a0, (void*)&a1, (void*)&a2, (void*)&a3 };
        if (hipLaunchCooperativeKernel(topk_ce_coop, dim3(CNBLK), dim3(CNTHR),
                                       args, 0, stream) == hipSuccess)
            return;
        (void)hipGetLastError();   // clear error, fall back
    }

    // Fallback: previous verified pipeline
    (void)hipMemsetAsync(ctrl, 0, CTRL_WORDS * sizeof(uint32_t), stream);
    loss_hist1<<<GRID, 256, 0, stream>>>(logits, labels, loss, hist1);
    scan_k<2048><<<BB, 256, 0, stream>>>(hist1, nullptr, sel1, cnt1);
    refine2<<<GRID, 256, 0, stream>>>(loss, hist2, sel1, sumAbove);
    scan_k<4096><<<BB, 256, 0, stream>>>(hist2, cnt1, sel2, cnt2);
    refine3<<<GRID, 256, 0, stream>>>(loss, hist3, sel1, sel2, sumAbove);
    finalize_k<<<1, 256, 0, stream>>>(hist3, sel1, sel2, cnt2, sumAbove, out);
}

// Round 3
// 688.016 us; speedup vs baseline: 1.2957x; 1.2957x over previous
//
#include <hip/hip_runtime.h>
#include <hip/hip_cooperative_groups.h>
#include <cstdint>

namespace cg = cooperative_groups;

// Problem constants
#define BB   8
#define CC   19
#define HWP  524288          // H*W pixels per batch row
#define NPIX 4194304         // B*H*W
#define KSEL 131072          // int(0.25 * HWP)

#define CNTHR 256

// Fallback config
#define GRID 4096

// ws layout:
//   [0, 16 MiB)  loss float[NPIX]   (fallback path only)
//   ctrl (u32 words) after:
#define LOSS_BYTES (NPIX * 4)
#define H1_OFF   0                       // hist1: 8*2048
#define H2_OFF   (8*2048)                // hist2: 8*4096
#define H3_OFF   (H2_OFF + 8*4096)      // hist3: 8*256
#define SEL1_OFF (H3_OFF + 8*256)       // 51200
#define CNT1_OFF (SEL1_OFF + 8)
#define SEL2_OFF (CNT1_OFF + 8)
#define CNT2_OFF (SEL2_OFF + 8)
#define PAD_OFF  (CNT2_OFF + 8)
#define SUMA_OFF (PAD_OFF + 2)          // word offset even -> byte offset %8==0
#define CTRL_WORDS (SUMA_OFF + 16)      // 8 doubles = 16 words

// ---------- block-level primitives (256 threads) ----------

__device__ __forceinline__ uint32_t block_incl_scan_u32(uint32_t v, volatile uint32_t* wt) {
    int lane = threadIdx.x & 63, wid = threadIdx.x >> 6;
    uint32_t inc = v;
#pragma unroll
    for (int off = 1; off < 64; off <<= 1) {
        uint32_t t = __shfl_up(inc, off);
        if (lane >= off) inc += t;
    }
    __syncthreads();                 // protect wt reuse across calls
    if (lane == 63) wt[wid] = inc;
    __syncthreads();
    for (int w = 0; w < wid; w++) inc += wt[w];
    return inc;
}

__device__ __forceinline__ double block_reduce_double(double v, volatile double* dwt) {
    int lane = threadIdx.x & 63, wid = threadIdx.x >> 6;
#pragma unroll
    for (int off = 32; off > 0; off >>= 1) v += __shfl_down(v, off);
    __syncthreads();
    if (lane == 0) dwt[wid] = v;
    __syncthreads();
    return dwt[0] + dwt[1] + dwt[2] + dwt[3];
}

__device__ __forceinline__ void block_sum_atomic(double sum, double* dst, volatile double* dwt) {
    double t = block_reduce_double(sum, dwt);
    if (threadIdx.x == 0 && t != 0.0) atomicAdd(dst, t);
}

// Descending radix-select over one row's NBINS histogram; every block computes
// its own row's answer (redundant across blocks of a row, L2-hot reads).
template <int NBINS>
__device__ __forceinline__ void row_select(
    const uint32_t* __restrict__ hrow, uint32_t prev,
    volatile uint32_t* wt, volatile uint32_t* shSel, volatile uint32_t* shCnt,
    uint32_t& sel, uint32_t& cnt)
{
    constexpr int CH = NBINS / 256;
    int base = NBINS - CH * ((int)threadIdx.x + 1);   // thread 0 owns TOP bins
    uint32_t hloc[CH];
    uint32_t csum = 0;
#pragma unroll
    for (int i = 0; i < CH; i++) { hloc[i] = hrow[base + i]; csum += hloc[i]; }
    uint32_t incl = block_incl_scan_u32(csum, wt);
    uint32_t pre = incl - csum;                       // count strictly above my chunk
    uint32_t target = (uint32_t)KSEL - prev;
    if (pre < target && pre + csum >= target) {
        uint32_t cum = pre;
#pragma unroll
        for (int i = CH - 1; i >= 0; i--) {
            uint32_t h = hloc[i];
            if (cum + h >= target) { *shSel = (uint32_t)(base + i); *shCnt = prev + cum; break; }
            cum += h;
        }
    }
    __syncthreads();
    sel = *shSel; cnt = *shCnt;
}

// ---------- single cooperative kernel: everything fused, loss in registers ----
// waves_per_eu(4,4): pin VGPR budget at 128 (4 blocks/CU co-residency) AND stop
// the allocator from shrinking to 64 + spilling (round-2 regression: VGPR=64,
// WRITE_SIZE +30MB scratch leak, 393 GB/s).
// Phase-1 logsumexp is computed in TWO channel chunks (10+9) with a single
// exact-when-dominant rescale, so peak live regs ~40 not 76.

template <int CBPR_T, int CGRP_T>
__global__ __attribute__((amdgpu_flat_work_group_size(256, 256), amdgpu_waves_per_eu(4, 4)))
void topk_ce_coop(
    const float* __restrict__ logits, const int* __restrict__ labels,
    uint32_t* __restrict__ ctrl, float* __restrict__ out)
{
    cg::grid_group grid = cg::this_grid();
    __shared__ uint32_t lh[4096];      // unioned: 2x2048 replicated (ph1) / 4096 (ph2) / 256 (ph3)
    __shared__ uint32_t wt[4];
    __shared__ double dwt[4];
    __shared__ uint32_t shSel, shCnt;

    uint32_t* hist1 = ctrl + H1_OFF;
    uint32_t* hist2 = ctrl + H2_OFF;
    uint32_t* hist3 = ctrl + H3_OFF;
    uint32_t* sel1g = ctrl + SEL1_OFF;
    uint32_t* sel2g = ctrl + SEL2_OFF;
    uint32_t* cnt2g = ctrl + CNT2_OFF;
    double* sumAbove = (double*)(ctrl + SUMA_OFF);

    const int tid = threadIdx.x;
    const int b = (int)blockIdx.x / CBPR_T;           // batch row
    const int rowblk = (int)blockIdx.x & (CBPR_T - 1);
    const int hrep = ((tid >> 6) & 1) << 11;          // warp-parity histogram replica

    // in-kernel zero of ctrl (poison-proof); completion guaranteed by sync #1
    for (int i = (int)blockIdx.x * CNTHR + tid; i < CTRL_WORDS; i += (int)gridDim.x * CNTHR)
        ctrl[i] = 0u;
    for (int i = tid; i < 4096; i += CNTHR) lh[i] = 0u;
    __syncthreads();

    // ---- phase 1: CE loss (split-channel logsumexp) + top-12-bit LDS hist
    const size_t rowbase = (size_t)b * CC * HWP;
    const size_t labbase = (size_t)b * HWP;
    const int prow0 = rowblk * (CNTHR * 4 * CGRP_T) + tid * 4;

    float4 lr[CGRP_T];
#pragma unroll
    for (int g = 0; g < CGRP_T; g++) {
        const int prow = prow0 + g * (CNTHR * 4);
        const float4* lg = (const float4*)(logits + rowbase + prow);
        const int4 lab = *(const int4*)(labels + labbase + prow);

        float g0 = 0.f, g1 = 0.f, g2 = 0.f, g3 = 0.f;
        float mA0, mA1, mA2, mA3, eA0, eA1, eA2, eA3;
        {   // chunk A: channels 0..9 (10 float4 live = 40 VGPR peak)
            float4 a[10];
#pragma unroll
            for (int c = 0; c < 10; c++) a[c] = lg[(size_t)c * (HWP / 4)];
            mA0 = a[0].x; mA1 = a[0].y; mA2 = a[0].z; mA3 = a[0].w;
#pragma unroll
            for (int c = 1; c < 10; c++) {
                mA0 = fmaxf(mA0, a[c].x); mA1 = fmaxf(mA1, a[c].y);
                mA2 = fmaxf(mA2, a[c].z); mA3 = fmaxf(mA3, a[c].w);
            }
            eA0 = 0.f; eA1 = 0.f; eA2 = 0.f; eA3 = 0.f;
#pragma unroll
            for (int c = 0; c < 10; c++) {
                eA0 += __expf(a[c].x - mA0); eA1 += __expf(a[c].y - mA1);
                eA2 += __expf(a[c].z - mA2); eA3 += __expf(a[c].w - mA3);
                g0 = (lab.x == c) ? a[c].x : g0;
                g1 = (lab.y == c) ? a[c].y : g1;
                g2 = (lab.z == c) ? a[c].z : g2;
                g3 = (lab.w == c) ? a[c].w : g3;
            }
        }
        float mB0, mB1, mB2, mB3, eB0, eB1, eB2, eB3;
        {   // chunk B: channels 10..18 (9 float4 live)
            float4 a[9];
#pragma unroll
            for (int c = 0; c < 9; c++) a[c] = lg[(size_t)(c + 10) * (HWP / 4)];
            mB0 = a[0].x; mB1 = a[0].y; mB2 = a[0].z; mB3 = a[0].w;
#pragma unroll
            for (int c = 1; c < 9; c++) {
                mB0 = fmaxf(mB0, a[c].x); mB1 = fmaxf(mB1, a[c].y);
                mB2 = fmaxf(mB2, a[c].z); mB3 = fmaxf(mB3, a[c].w);
            }
            eB0 = 0.f; eB1 = 0.f; eB2 = 0.f; eB3 = 0.f;
#pragma unroll
            for (int c = 0; c < 9; c++) {
                eB0 += __expf(a[c].x - mB0); eB1 += __expf(a[c].y - mB1);
                eB2 += __expf(a[c].z - mB2); eB3 += __expf(a[c].w - mB3);
                g0 = (lab.x == c + 10) ? a[c].x : g0;
                g1 = (lab.y == c + 10) ? a[c].y : g1;
                g2 = (lab.z == c + 10) ? a[c].z : g2;
                g3 = (lab.w == c + 10) ? a[c].w : g3;
            }
        }
        // combine: one scale is exp(0)==1 exactly
        float m0 = fmaxf(mA0, mB0), m1 = fmaxf(mA1, mB1);
        float m2 = fmaxf(mA2, mB2), m3 = fmaxf(mA3, mB3);
        float e0 = eA0 * __expf(mA0 - m0) + eB0 * __expf(mB0 - m0);
        float e1 = eA1 * __expf(mA1 - m1) + eB1 * __expf(mB1 - m1);
        float e2 = eA2 * __expf(mA2 - m2) + eB2 * __expf(mB2 - m2);
        float e3 = eA3 * __expf(mA3 - m3) + eB3 * __expf(mB3 - m3);

        float l0 = fmaxf(m0 + __logf(e0) - g0, 0.f);
        float l1 = fmaxf(m1 + __logf(e1) - g1, 0.f);
        float l2 = fmaxf(m2 + __logf(e2) - g2, 0.f);
        float l3 = fmaxf(m3 + __logf(e3) - g3, 0.f);
        lr[g] = make_float4(l0, l1, l2, l3);

        atomicAdd(&lh[hrep + (__float_as_uint(l0) >> 20)], 1u);
        atomicAdd(&lh[hrep + (__float_as_uint(l1) >> 20)], 1u);
        atomicAdd(&lh[hrep + (__float_as_uint(l2) >> 20)], 1u);
        atomicAdd(&lh[hrep + (__float_as_uint(l3) >> 20)], 1u);
    }
    __syncthreads();
    grid.sync();                                   // #1: ctrl zeroing complete everywhere
    for (int i = tid; i < 2048; i += CNTHR) {
        uint32_t v = lh[i] + lh[i + 2048];
        if (v) atomicAdd(&hist1[b * 2048 + i], v);
    }
    grid.sync();                                   // #2: hist1 complete

    // ---- phase 2: local sel1, sum-above + mid-12-bit hist (loss from registers)
    uint32_t sel1v, cnt1v;
    row_select<2048>(hist1 + b * 2048, 0u, wt, &shSel, &shCnt, sel1v, cnt1v);
    __syncthreads();
    for (int i = tid; i < 4096; i += CNTHR) lh[i] = 0u;
    __syncthreads();

    double sum = 0.0;
#pragma unroll
    for (int g = 0; g < CGRP_T; g++) {
        float vv[4] = {lr[g].x, lr[g].y, lr[g].z, lr[g].w};
#pragma unroll
        for (int j = 0; j < 4; j++) {
            uint32_t u = __float_as_uint(vv[j]);
            uint32_t t = u >> 20;
            if (t > sel1v) sum += (double)vv[j];
            else if (t == sel1v) atomicAdd(&lh[(u >> 8) & 0xFFFu], 1u);
        }
    }
    __syncthreads();
    block_sum_atomic(sum, &sumAbove[b], dwt);
    for (int i = tid; i < 4096; i += CNTHR) {
        uint32_t v = lh[i];
        if (v) atomicAdd(&hist2[b * 4096 + i], v);
    }
    if (rowblk == 0 && tid == 0) sel1g[b] = sel1v;
    grid.sync();                                   // #3: hist2 complete

    // ---- phase 3: local sel2, sum-above + exact low-8-bit hist
    uint32_t sel2v, cnt2v;
    row_select<4096>(hist2 + b * 4096, cnt1v, wt, &shSel, &shCnt, sel2v, cnt2v);
    __syncthreads();
    lh[tid] = 0u;
    __syncthreads();

    double sum2 = 0.0;
#pragma unroll
    for (int g = 0; g < CGRP_T; g++) {
        float vv[4] = {lr[g].x, lr[g].y, lr[g].z, lr[g].w};
#pragma unroll
        for (int j = 0; j < 4; j++) {
            uint32_t u = __float_as_uint(vv[j]);
            if ((u >> 20) == sel1v) {
                uint32_t mid = (u >> 8) & 0xFFFu;
                if (mid > sel2v) sum2 += (double)vv[j];
                else if (mid == sel2v) atomicAdd(&lh[u & 0xFFu], 1u);
            }
        }
    }
    __syncthreads();
    block_sum_atomic(sum2, &sumAbove[b], dwt);
    {
        uint32_t c = lh[tid];
        if (c) atomicAdd(&hist3[b * 256 + tid], c);
    }
    if (rowblk == 0 && tid == 0) { sel2g[b] = sel2v; cnt2g[b] = cnt2v; }
    grid.sync();                                   // #4: hist3 + sumAbove complete

    // ---- finalize: block 0, tie-corrected closed-form top-k mean
    if (blockIdx.x == 0) {
        double tot = 0.0;
        for (int r = 0; r < BB; r++) {
            int b3 = 255 - tid;
            uint32_t h = hist3[r * 256 + b3];
            uint32_t incl = block_incl_scan_u32(h, wt);
            uint32_t pre = incl - h;
            uint32_t rem = (uint32_t)KSEL - cnt2g[r];
            uint32_t take = (rem > pre) ? ((rem - pre < h) ? (rem - pre) : h) : 0u;
            uint32_t P = (sel1g[r] << 20) | (sel2g[r] << 8) | (uint32_t)b3;
            double contrib = (double)take * (double)__uint_as_float(P);
            double s = block_reduce_double(contrib, dwt);
            if (tid == 0) tot += s + sumAbove[r];
        }
        if (tid == 0) out[0] = (float)(tot / ((double)BB * (double)KSEL));
    }
}

// ================= fallback: previous verified 6-kernel pipeline ==============

__global__ __launch_bounds__(256) void loss_hist1(
    const float* __restrict__ logits, const int* __restrict__ labels,
    float* __restrict__ loss, uint32_t* __restrict__ hist1)
{
    __shared__ uint32_t lh[2048];
    for (int i = threadIdx.x; i < 2048; i += 256) lh[i] = 0u;
    __syncthreads();

    int b = blockIdx.x >> 9;
    int pix0 = blockIdx.x * 1024 + threadIdx.x * 4;
    int prow = pix0 & (HWP - 1);

    const float4* lg = (const float4*)(logits + (size_t)b * CC * HWP + prow);
    float4 a[CC];
#pragma unroll
    for (int c = 0; c < CC; c++) a[c] = lg[(size_t)c * (HWP / 4)];

    int4 lab = *(const int4*)(labels + pix0);

    float mx0 = a[0].x, mx1 = a[0].y, mx2 = a[0].z, mx3 = a[0].w;
#pragma unroll
    for (int c = 1; c < CC; c++) {
        mx0 = fmaxf(mx0, a[c].x); mx1 = fmaxf(mx1, a[c].y);
        mx2 = fmaxf(mx2, a[c].z); mx3 = fmaxf(mx3, a[c].w);
    }
    float g0 = 0.f, g1 = 0.f, g2 = 0.f, g3 = 0.f;
    float e0 = 0.f, e1 = 0.f, e2 = 0.f, e3 = 0.f;
#pragma unroll
    for (int c = 0; c < CC; c++) {
        e0 += __expf(a[c].x - mx0); e1 += __expf(a[c].y - mx1);
        e2 += __expf(a[c].z - mx2); e3 += __expf(a[c].w - mx3);
        g0 = (lab.x == c) ? a[c].x : g0;
        g1 = (lab.y == c) ? a[c].y : g1;
        g2 = (lab.z == c) ? a[c].z : g2;
        g3 = (lab.w == c) ? a[c].w : g3;
    }
    float l0 = fmaxf(mx0 + __logf(e0) - g0, 0.f);
    float l1 = fmaxf(mx1 + __logf(e1) - g1, 0.f);
    float l2 = fmaxf(mx2 + __logf(e2) - g2, 0.f);
    float l3 = fmaxf(mx3 + __logf(e3) - g3, 0.f);

    float4 o; o.x = l0; o.y = l1; o.z = l2; o.w = l3;
    *(float4*)(loss + pix0) = o;

    atomicAdd(&lh[__float_as_uint(l0) >> 20], 1u);
    atomicAdd(&lh[__float_as_uint(l1) >> 20], 1u);
    atomicAdd(&lh[__float_as_uint(l2) >> 20], 1u);
    atomicAdd(&lh[__float_as_uint(l3) >> 20], 1u);

    __syncthreads();
    for (int i = threadIdx.x; i < 2048; i += 256) {
        uint32_t v = lh[i];
        if (v) atomicAdd(&hist1[b * 2048 + i], v);
    }
}

template <int NBINS>
__global__ __launch_bounds__(256) void scan_k(
    const uint32_t* __restrict__ hist, const uint32_t* __restrict__ cntPrev,
    uint32_t* __restrict__ selOut, uint32_t* __restrict__ cntOut)
{
    __shared__ uint32_t wt[4];
    constexpr int CH = NBINS / 256;
    int r = blockIdx.x;
    const uint32_t* hrow = hist + r * NBINS;
    int base = NBINS - CH * ((int)threadIdx.x + 1);
    uint32_t hloc[CH];
    uint32_t csum = 0;
#pragma unroll
    for (int i = 0; i < CH; i++) { hloc[i] = hrow[base + i]; csum += hloc[i]; }
    uint32_t incl = block_incl_scan_u32(csum, wt);
    uint32_t pre = incl - csum;
    uint32_t prev = cntPrev ? cntPrev[r] : 0u;
    uint32_t target = (uint32_t)KSEL - prev;
    if (pre < target && pre + csum >= target) {
        uint32_t cum = pre;
#pragma unroll
        for (int i = CH - 1; i >= 0; i--) {
            uint32_t h = hloc[i];
            if (cum + h >= target) { selOut[r] = (uint32_t)(base + i); cntOut[r] = prev + cum; break; }
            cum += h;
        }
    }
}

__global__ __launch_bounds__(256) void refine2(
    const float* __restrict__ loss, uint32_t* __restrict__ hist2,
    const uint32_t* __restrict__ sel1, double* __restrict__ sumAbove)
{
    __shared__ uint32_t lh[4096];
    __shared__ double dwt[4];
    for (int i = threadIdx.x; i < 4096; i += 256) lh[i] = 0u;
    __syncthreads();

    int b = blockIdx.x >> 9;
    uint32_t s1 = sel1[b];
    int pix0 = blockIdx.x * 1024 + threadIdx.x * 4;
    float4 v = *(const float4*)(loss + pix0);

    double sum = 0.0;
    {
        float vv[4] = {v.x, v.y, v.z, v.w};
#pragma unroll
        for (int j = 0; j < 4; j++) {
            uint32_t u = __float_as_uint(vv[j]);
            uint32_t t = u >> 20;
            if (t > s1) sum += (double)vv[j];
            else if (t == s1) atomicAdd(&lh[(u >> 8) & 0xFFFu], 1u);
        }
    }
    __syncthreads();
    block_sum_atomic(sum, &sumAbove[b], dwt);
    for (int i = threadIdx.x; i < 4096; i += 256) {
        uint32_t c = lh[i];
        if (c) atomicAdd(&hist2[b * 4096 + i], c);
    }
}

__global__ __launch_bounds__(256) void refine3(
    const float* __restrict__ loss, uint32_t* __restrict__ hist3,
    const uint32_t* __restrict__ sel1, const uint32_t* __restrict__ sel2,
    double* __restrict__ sumAbove)
{
    __shared__ uint32_t lh[256];
    __shared__ double dwt[4];
    lh[threadIdx.x] = 0u;
    __syncthreads();

    int b = blockIdx.x >> 9;
    uint32_t s1 = sel1[b], s2 = sel2[b];
    int pix0 = blockIdx.x * 1024 + threadIdx.x * 4;
    float4 v = *(const float4*)(loss + pix0);

    double sum = 0.0;
    {
        float vv[4] = {v.x, v.y, v.z, v.w};
#pragma unroll
        for (int j = 0; j < 4; j++) {
            uint32_t u = __float_as_uint(vv[j]);
            if ((u >> 20) == s1) {
                uint32_t mid = (u >> 8) & 0xFFFu;
                if (mid > s2) sum += (double)vv[j];
                else if (mid == s2) atomicAdd(&lh[u & 0xFFu], 1u);
            }
        }
    }
    __syncthreads();
    block_sum_atomic(sum, &sumAbove[b], dwt);
    {
        uint32_t c = lh[threadIdx.x];
        if (c) atomicAdd(&hist3[b * 256 + threadIdx.x], c);
    }
}

__global__ __launch_bounds__(256) void finalize_k(
    const uint32_t* __restrict__ hist3,
    const uint32_t* __restrict__ sel1, const uint32_t* __restrict__ sel2,
    const uint32_t* __restrict__ cnt2, const double* __restrict__ sumAbove,
    float* __restrict__ out)
{
    __shared__ uint32_t wt[4];
    __shared__ double dwt[4];
    double tot = 0.0;
    for (int r = 0; r < BB; r++) {
        int b3 = 255 - (int)threadIdx.x;
        uint32_t h = hist3[r * 256 + b3];
        uint32_t incl = block_incl_scan_u32(h, wt);
        uint32_t pre = incl - h;
        uint32_t rem = (uint32_t)KSEL - cnt2[r];
        uint32_t take = (rem > pre) ? ((rem - pre < h) ? (rem - pre) : h) : 0u;
        uint32_t P = (sel1[r] << 20) | (sel2[r] << 8) | (uint32_t)b3;
        double contrib = (double)take * (double)__uint_as_float(P);
        double s = block_reduce_double(contrib, dwt);
        if (threadIdx.x == 0) tot += s + sumAbove[r];
    }
    if (threadIdx.x == 0) out[0] = (float)(tot / ((double)BB * (double)KSEL));
}

extern "C" void kernel_launch(void* const* d_in, const int* in_sizes, int n_in,
                              void* d_out, int out_size, void* d_ws, size_t ws_size,
                              hipStream_t stream)
{
    const float* logits = (const float*)d_in[0];
    const int* labels   = (const int*)d_in[1];
    float* out          = (float*)d_out;

    char* ws = (char*)d_ws;
    float* loss      = (float*)ws;                   // fallback only
    uint32_t* ctrl   = (uint32_t*)(ws + LOSS_BYTES);
    uint32_t* hist1  = ctrl + H1_OFF;
    uint32_t* hist2  = ctrl + H2_OFF;
    uint32_t* hist3  = ctrl + H3_OFF;
    uint32_t* sel1   = ctrl + SEL1_OFF;
    uint32_t* cnt1   = ctrl + CNT1_OFF;
    uint32_t* sel2   = ctrl + SEL2_OFF;
    uint32_t* cnt2   = ctrl + CNT2_OFF;
    double* sumAbove = (double*)(ctrl + SUMA_OFF);

    // Primary: single cooperative kernel; pick grid by measured co-residency.
    {
        const float* a0 = logits;
        const int*   a1 = labels;
        uint32_t*    a2 = ctrl;
        float*       a3 = out;
        void* args[4] = { (void*)&a0, (void*)&a1, (void*)&a2, (void*)&a3 };

        int nb4 = 0;
        if (hipOccupancyMaxActiveBlocksPerMultiprocessor(&nb4, topk_ce_coop<128, 4>, CNTHR, 0) == hipSuccess
            && nb4 >= 4) {
            if (hipLaunchCooperativeKernel(topk_ce_coop<128, 4>, dim3(128 * BB), dim3(CNTHR),
                                           args, 0, stream) == hipSuccess)
                return;
            (void)hipGetLastError();
        }
        int nb2 = 0;
        if (hipOccupancyMaxActiveBlocksPerMultiprocessor(&nb2, topk_ce_coop<64, 8>, CNTHR, 0) == hipSuccess
            && nb2 >= 2) {
            if (hipLaunchCooperativeKernel(topk_ce_coop<64, 8>, dim3(64 * BB), dim3(CNTHR),
                                           args, 0, stream) == hipSuccess)
                return;
            (void)hipGetLastError();
        }
    }

    // Fallback: previous verified pipeline
    (void)hipMemsetAsync(ctrl, 0, CTRL_WORDS * sizeof(uint32_t), stream);
    loss_hist1<<<GRID, 256, 0, stream>>>(logits, labels, loss, hist1);
    scan_k<2048><<<BB, 256, 0, stream>>>(hist1, nullptr, sel1, cnt1);
    refine2<<<GRID, 256, 0, stream>>>(loss, hist2, sel1, sumAbove);
    scan_k<4096><<<BB, 256, 0, stream>>>(hist2, cnt1, sel2, cnt2);
    refine3<<<GRID, 256, 0, stream>>>(loss, hist3, sel1, sel2, sumAbove);
    finalize_k<<<1, 256, 0, stream>>>(hist3, sel1, sel2, cnt2, sumAbove, out);
}

// Round 4
// 541.594 us; speedup vs baseline: 1.6460x; 1.2704x over previous
//
#include <hip/hip_runtime.h>
#include <cstdint>

// Problem constants
#define BB   8
#define CC   19
#define HWP  524288          // H*W pixels per batch row
#define NPIX 4194304         // B*H*W
#define KSEL 131072          // int(0.25 * HWP)
#define GRID 4096            // blocks for the 3 wide kernels

// ws layout:
//   [0, 16 MiB)  loss float[NPIX]
//   ctrl (u32 words, zeroed via hipMemsetAsync each launch):
#define H1_OFF   0                       // hist1: 8*2048
#define H2_OFF   (8*2048)                // hist2: 8*4096
#define H3_OFF   (H2_OFF + 8*4096)      // hist3: 8*256
#define SEL1_OFF (H3_OFF + 8*256)       // 51200
#define CNT1_OFF (SEL1_OFF + 8)
#define SEL2_OFF (CNT1_OFF + 8)
#define CNT2_OFF (SEL2_OFF + 8)
#define PAD_OFF  (CNT2_OFF + 8)         // pad
#define SUMA_OFF (PAD_OFF + 2)          // byte offset %8==0 -> double-aligned
#define CTRL_WORDS (SUMA_OFF + 16)      // 8 doubles = 16 words
#define LOSS_BYTES (NPIX * 4)

// ---------- block-level primitives (256 threads) ----------

__device__ __forceinline__ uint32_t block_incl_scan_u32(uint32_t v, volatile uint32_t* wt) {
    int lane = threadIdx.x & 63, wid = threadIdx.x >> 6;
    uint32_t inc = v;
#pragma unroll
    for (int off = 1; off < 64; off <<= 1) {
        uint32_t t = __shfl_up(inc, off);
        if (lane >= off) inc += t;
    }
    __syncthreads();                 // protect wt reuse across calls
    if (lane == 63) wt[wid] = inc;
    __syncthreads();
    for (int w = 0; w < wid; w++) inc += wt[w];
    return inc;
}

__device__ __forceinline__ double block_reduce_double(double v, volatile double* dwt) {
    int lane = threadIdx.x & 63, wid = threadIdx.x >> 6;
#pragma unroll
    for (int off = 32; off > 0; off >>= 1) v += __shfl_down(v, off);
    __syncthreads();
    if (lane == 0) dwt[wid] = v;
    __syncthreads();
    return dwt[0] + dwt[1] + dwt[2] + dwt[3];
}

__device__ __forceinline__ void block_sum_atomic(double sum, double* dst, volatile double* dwt) {
    double t = block_reduce_double(sum, dwt);
    if (threadIdx.x == 0 && t != 0.0) atomicAdd(dst, t);
}

// Descending radix-select over one row's NBINS histogram. Every calling block
// computes its row's answer redundantly (8-16KB L2-hot reads) — validated in
// the coop-kernel rounds (absmax 0.0). Exactly one thread fires the write.
template <int NBINS>
__device__ __forceinline__ void row_select(
    const uint32_t* __restrict__ hrow, uint32_t prev,
    volatile uint32_t* wt, volatile uint32_t* shSel, volatile uint32_t* shCnt,
    uint32_t& sel, uint32_t& cnt)
{
    constexpr int CH = NBINS / 256;
    int base = NBINS - CH * ((int)threadIdx.x + 1);   // thread 0 owns TOP bins
    uint32_t hloc[CH];
    uint32_t csum = 0;
#pragma unroll
    for (int i = 0; i < CH; i++) { hloc[i] = hrow[base + i]; csum += hloc[i]; }
    uint32_t incl = block_incl_scan_u32(csum, wt);
    uint32_t pre = incl - csum;                       // count strictly above my chunk
    uint32_t target = (uint32_t)KSEL - prev;
    if (pre < target && pre + csum >= target) {
        uint32_t cum = pre;
#pragma unroll
        for (int i = CH - 1; i >= 0; i--) {
            uint32_t h = hloc[i];
            if (cum + h >= target) { *shSel = (uint32_t)(base + i); *shCnt = prev + cum; break; }
            cum += h;
        }
    }
    __syncthreads();
    sel = *shSel; cnt = *shCnt;
}

// ---------- K1: fused CE loss + top-12-bit histogram (verified round-0 code) --

__global__ __launch_bounds__(256) void loss_hist1(
    const float* __restrict__ logits, const int* __restrict__ labels,
    float* __restrict__ loss, uint32_t* __restrict__ hist1)
{
    __shared__ uint32_t lh[2048];
    for (int i = threadIdx.x; i < 2048; i += 256) lh[i] = 0u;
    __syncthreads();

    int b = blockIdx.x >> 9;                       // 512 blocks per batch row
    int pix0 = blockIdx.x * 1024 + threadIdx.x * 4;
    int prow = pix0 & (HWP - 1);

    const float4* lg = (const float4*)(logits + (size_t)b * CC * HWP + prow);
    float4 a[CC];
#pragma unroll
    for (int c = 0; c < CC; c++) a[c] = lg[(size_t)c * (HWP / 4)];

    int4 lab = *(const int4*)(labels + pix0);

    float mx0 = a[0].x, mx1 = a[0].y, mx2 = a[0].z, mx3 = a[0].w;
#pragma unroll
    for (int c = 1; c < CC; c++) {
        mx0 = fmaxf(mx0, a[c].x); mx1 = fmaxf(mx1, a[c].y);
        mx2 = fmaxf(mx2, a[c].z); mx3 = fmaxf(mx3, a[c].w);
    }
    float g0 = 0.f, g1 = 0.f, g2 = 0.f, g3 = 0.f;
    float e0 = 0.f, e1 = 0.f, e2 = 0.f, e3 = 0.f;
#pragma unroll
    for (int c = 0; c < CC; c++) {
        e0 += __expf(a[c].x - mx0); e1 += __expf(a[c].y - mx1);
        e2 += __expf(a[c].z - mx2); e3 += __expf(a[c].w - mx3);
        g0 = (lab.x == c) ? a[c].x : g0;
        g1 = (lab.y == c) ? a[c].y : g1;
        g2 = (lab.z == c) ? a[c].z : g2;
        g3 = (lab.w == c) ? a[c].w : g3;
    }
    // CE >= 0 mathematically; clamp guards the bit-histogram from sign-bit flukes.
    float l0 = fmaxf(mx0 + __logf(e0) - g0, 0.f);
    float l1 = fmaxf(mx1 + __logf(e1) - g1, 0.f);
    float l2 = fmaxf(mx2 + __logf(e2) - g2, 0.f);
    float l3 = fmaxf(mx3 + __logf(e3) - g3, 0.f);

    float4 o; o.x = l0; o.y = l1; o.z = l2; o.w = l3;
    *(float4*)(loss + pix0) = o;

    atomicAdd(&lh[__float_as_uint(l0) >> 20], 1u);
    atomicAdd(&lh[__float_as_uint(l1) >> 20], 1u);
    atomicAdd(&lh[__float_as_uint(l2) >> 20], 1u);
    atomicAdd(&lh[__float_as_uint(l3) >> 20], 1u);

    __syncthreads();
    for (int i = threadIdx.x; i < 2048; i += 256) {
        uint32_t v = lh[i];
        if (v) atomicAdd(&hist1[b * 2048 + i], v);
    }
}

// ---------- K2: fused sel1-select + sum-above + mid-12-bit refine ----------
// Replaces scan_k<2048> + refine2 (dispatch count 7 -> 5; removes the
// 8-block whole-GPU-idle scan dispatch).

__global__ __launch_bounds__(256) void refine2s(
    const float* __restrict__ loss, const uint32_t* __restrict__ hist1,
    uint32_t* __restrict__ hist2,
    uint32_t* __restrict__ sel1g, uint32_t* __restrict__ cnt1g,
    double* __restrict__ sumAbove)
{
    __shared__ uint32_t lh[4096];
    __shared__ uint32_t wt[4];
    __shared__ double dwt[4];
    __shared__ uint32_t shSel, shCnt;
    for (int i = threadIdx.x; i < 4096; i += 256) lh[i] = 0u;
    __syncthreads();

    int b = blockIdx.x >> 9;
    int rowblk = blockIdx.x & 511;

    uint32_t s1, c1;
    row_select<2048>(hist1 + b * 2048, 0u, wt, &shSel, &shCnt, s1, c1);
    if (rowblk == 0 && threadIdx.x == 0) { sel1g[b] = s1; cnt1g[b] = c1; }
    __syncthreads();

    int pix0 = blockIdx.x * 1024 + threadIdx.x * 4;
    float4 v = *(const float4*)(loss + pix0);

    double sum = 0.0;
    {
        float vv[4] = {v.x, v.y, v.z, v.w};
#pragma unroll
        for (int j = 0; j < 4; j++) {
            uint32_t u = __float_as_uint(vv[j]);
            uint32_t t = u >> 20;
            if (t > s1) sum += (double)vv[j];
            else if (t == s1) atomicAdd(&lh[(u >> 8) & 0xFFFu], 1u);
        }
    }
    __syncthreads();
    block_sum_atomic(sum, &sumAbove[b], dwt);
    for (int i = threadIdx.x; i < 4096; i += 256) {
        uint32_t c = lh[i];
        if (c) atomicAdd(&hist2[b * 4096 + i], c);
    }
}

// ---------- K3: fused sel2-select + sum-above + low-8-bit refine ----------
// Replaces scan_k<4096> + refine3.

__global__ __launch_bounds__(256) void refine3s(
    const float* __restrict__ loss, const uint32_t* __restrict__ hist2,
    uint32_t* __restrict__ hist3,
    const uint32_t* __restrict__ sel1g, const uint32_t* __restrict__ cnt1g,
    uint32_t* __restrict__ sel2g, uint32_t* __restrict__ cnt2g,
    double* __restrict__ sumAbove)
{
    __shared__ uint32_t lh[256];
    __shared__ uint32_t wt[4];
    __shared__ double dwt[4];
    __shared__ uint32_t shSel, shCnt;
    lh[threadIdx.x] = 0u;
    __syncthreads();

    int b = blockIdx.x >> 9;
    int rowblk = blockIdx.x & 511;
    uint32_t s1 = sel1g[b];
    uint32_t c1 = cnt1g[b];

    uint32_t s2, c2;
    row_select<4096>(hist2 + b * 4096, c1, wt, &shSel, &shCnt, s2, c2);
    if (rowblk == 0 && threadIdx.x == 0) { sel2g[b] = s2; cnt2g[b] = c2; }
    __syncthreads();

    int pix0 = blockIdx.x * 1024 + threadIdx.x * 4;
    float4 v = *(const float4*)(loss + pix0);

    double sum = 0.0;
    {
        float vv[4] = {v.x, v.y, v.z, v.w};
#pragma unroll
        for (int j = 0; j < 4; j++) {
            uint32_t u = __float_as_uint(vv[j]);
            if ((u >> 20) == s1) {
                uint32_t mid = (u >> 8) & 0xFFFu;
                if (mid > s2) sum += (double)vv[j];
                else if (mid == s2) atomicAdd(&lh[u & 0xFFu], 1u);
            }
        }
    }
    __syncthreads();
    block_sum_atomic(sum, &sumAbove[b], dwt);
    {
        uint32_t c = lh[threadIdx.x];
        if (c) atomicAdd(&hist3[b * 256 + threadIdx.x], c);
    }
}

// ---------- finalize: parallel closed-form tie-corrected top-k sum ----------
// hist3 bins are EXACT float bit patterns. Thread t owns bin 255-t.

__global__ __launch_bounds__(256) void finalize_k(
    const uint32_t* __restrict__ hist3,
    const uint32_t* __restrict__ sel1, const uint32_t* __restrict__ sel2,
    const uint32_t* __restrict__ cnt2, const double* __restrict__ sumAbove,
    float* __restrict__ out)
{
    __shared__ uint32_t wt[4];
    __shared__ double dwt[4];
    double tot = 0.0;
    for (int r = 0; r < BB; r++) {
        int b3 = 255 - (int)threadIdx.x;
        uint32_t h = hist3[r * 256 + b3];
        uint32_t incl = block_incl_scan_u32(h, wt);
        uint32_t pre = incl - h;                       // count in bins above b3
        uint32_t rem = (uint32_t)KSEL - cnt2[r];
        uint32_t take = (rem > pre) ? ((rem - pre < h) ? (rem - pre) : h) : 0u;
        uint32_t P = (sel1[r] << 20) | (sel2[r] << 8) | (uint32_t)b3;
        double contrib = (double)take * (double)__uint_as_float(P);
        double s = block_reduce_double(contrib, dwt);
        if (threadIdx.x == 0) tot += s + sumAbove[r];
    }
    if (threadIdx.x == 0) out[0] = (float)(tot / ((double)BB * (double)KSEL));
}

extern "C" void kernel_launch(void* const* d_in, const int* in_sizes, int n_in,
                              void* d_out, int out_size, void* d_ws, size_t ws_size,
                              hipStream_t stream)
{
    const float* logits = (const float*)d_in[0];
    const int* labels   = (const int*)d_in[1];
    float* out          = (float*)d_out;

    char* ws = (char*)d_ws;
    float* loss      = (float*)ws;
    uint32_t* ctrl   = (uint32_t*)(ws + LOSS_BYTES);
    uint32_t* hist1  = ctrl + H1_OFF;
    uint32_t* hist2  = ctrl + H2_OFF;
    uint32_t* hist3  = ctrl + H3_OFF;
    uint32_t* sel1   = ctrl + SEL1_OFF;
    uint32_t* cnt1   = ctrl + CNT1_OFF;
    uint32_t* sel2   = ctrl + SEL2_OFF;
    uint32_t* cnt2   = ctrl + CNT2_OFF;
    double* sumAbove = (double*)(ctrl + SUMA_OFF);

    (void)hipMemsetAsync(ctrl, 0, CTRL_WORDS * sizeof(uint32_t), stream);
    loss_hist1<<<GRID, 256, 0, stream>>>(logits, labels, loss, hist1);
    refine2s<<<GRID, 256, 0, stream>>>(loss, hist1, hist2, sel1, cnt1, sumAbove);
    refine3s<<<GRID, 256, 0, stream>>>(loss, hist2, hist3, sel1, cnt1, sel2, cnt2, sumAbove);
    finalize_k<<<1, 256, 0, stream>>>(hist3, sel1, sel2, cnt2, sumAbove, out);
}